// Round 4
// baseline (1170.210 us; speedup 1.0000x reference)
//
#include <hip/hip_runtime.h>

// ---------------- constants ----------------
constexpr int   kNA     = 25200;
constexpr int   kStride = 117;      // 4 box + 1 obj + 80 cls + 32 coef
constexpr int   kNC     = 80;
constexpr int   kNM     = 32;
constexpr int   kTopK   = 1024;
constexpr int   kMaxDet = 300;
constexpr int   kImg    = 640;
constexpr int   kPHW    = 160;
constexpr float kConfT  = 0.25f;
constexpr float kIouT   = 0.45f;
constexpr float kMaxWH  = 7680.0f;

constexpr unsigned long long kMaskElems = 300ull * 640ull * 640ull; // 122,880,000

typedef float v4f __attribute__((ext_vector_type(4)));

// mask region geometry in float4 quads
constexpr size_t   kN4        = 61440000;   // total quads (983 MB)
constexpr size_t   kQSlices   = 30720000;   // quads in the f-region (300 slices)
constexpr unsigned kQPerSlice = 102400;     // 640*640/4
constexpr unsigned kQPerRow   = 160;        // 640/4

// pre-zero partition (linear, full-rate; sized to hide under each serial stage)
constexpr size_t kZ0 = 5000000;      // decode share  (80 MB)
constexpr size_t kZ1 = 14500000;     // topk share    (152 MB)
constexpr size_t kZ2 = 18000000;     // supmat share  (56 MB)
constexpr size_t kZ3 = 24000000;     // nms share     (96 MB)
// finalize zeroes [kZ3, kN4) minus patch-owned quads (599 MB - 33 MB)

constexpr int kZDecB  = 1024;  // extra 128-thr zero blocks in decode_k
constexpr int kZTopkB = 512;   // extra 1024-thr zero blocks in topk_k
constexpr int kZSupB  = 384;   // extra 256-thr zero blocks in supmat_k
constexpr int kZNmsB  = 768;   // extra 256-thr zero blocks in nms_k
constexpr int kZFinB  = 2048;  // extra 256-thr zero blocks in finalize_k

// ---------------- ws layout (bytes) ----------------
constexpr size_t O_SCORES = 0;        // 25200 f32
constexpr size_t O_BOXES  = 100864;   // 25200*4 f32 (16B aligned)
constexpr size_t O_CLS    = 504064;   // 25200 i32
constexpr size_t O_TKIDX  = 604864;   // 1024 i32
constexpr size_t O_TKSC   = 608960;   // 1024 f32
constexpr size_t O_TKBOX  = 613056;   // 1024*4 f32
constexpr size_t O_TKNBOX = 629440;   // 1024*4 f32 (class-offset boxes)
constexpr size_t O_TKCLS  = 645824;   // 1024 i32
constexpr size_t O_SUP    = 649984;   // 1024*16 u64 = 131072
constexpr size_t O_NDET   = 782336;   // 1 i32
constexpr size_t O_DBOX   = 782400;   // 300*4 f32
constexpr size_t O_DCOEF  = 787264;   // 300*32 f32
constexpr size_t O_ROWR   = 825664;   // 300 int4 (i_lo,i_hi,jq_lo,jq_hi; empty=(1,0,1,0))
// total < 1 MB

// ---------------- kernel 1: decode (LDS-staged) + zero share [0, kZ0) ---------
constexpr int kDecRows = 64;
constexpr int kDecThr  = 128;
constexpr int kDecBlocks = (kNA + kDecRows - 1) / kDecRows;   // 394
__global__ __launch_bounds__(kDecThr) void decode_k(const float* __restrict__ pred,
        float* __restrict__ scores, float* __restrict__ boxes, int* __restrict__ cls,
        float* __restrict__ outz) {
    if (blockIdx.x >= kDecBlocks) {      // zero-fill blocks
        v4f z = 0.f;
        size_t stride = (size_t)(gridDim.x - kDecBlocks) * kDecThr;
        for (size_t i = (size_t)(blockIdx.x - kDecBlocks) * kDecThr + threadIdx.x;
             i < kZ0; i += stride)
            __builtin_nontemporal_store(z, ((v4f*)outz) + i);
        return;
    }
    __shared__ float rows[kDecRows * kStride];   // 29,952 B -> 5 blocks/CU
    int base = blockIdx.x * kDecRows;
    int nrows = min(kDecRows, kNA - base);
    int total = nrows * kStride;
    const float* src = pred + (size_t)base * kStride;
    for (int i = threadIdx.x; i < total; i += kDecThr) rows[i] = src[i];
    __syncthreads();
    int r = threadIdx.x;
    if (r >= nrows) return;
    int a = base + r;
    const float* p = rows + r * kStride;
    float obj = p[4];
    float best = -1.0f; int bj = 0;
    for (int c = 0; c < kNC; ++c) {
        float v = p[5 + c] * obj;           // same single-rounding product as reference
        if (v > best) { best = v; bj = c; } // strict > keeps first max (argmax semantics)
    }
    bool valid = (obj > kConfT) && (best > kConfT);
    scores[a] = valid ? best : -1.0f;
    float cx = p[0], cy = p[1], w = p[2], h = p[3];
    float hw = w * 0.5f, hh = h * 0.5f;
    boxes[4*a+0] = cx - hw; boxes[4*a+1] = cy - hh;
    boxes[4*a+2] = cx + hw; boxes[4*a+3] = cy + hh;
    cls[a] = bj;
}

// ---------------- kernel 2: exact top-1024 (block 0) + zero share --------------
__device__ __forceinline__ unsigned f2ord(float f) {
    unsigned b = __float_as_uint(f);
    return (b & 0x80000000u) ? ~b : (b | 0x80000000u);
}
__device__ __forceinline__ float ord2f(unsigned u) {
    unsigned b = (u & 0x80000000u) ? (u ^ 0x80000000u) : ~u;
    return __uint_as_float(b);
}

__global__ __launch_bounds__(1024) void topk_k(const float* __restrict__ scores,
        const float* __restrict__ boxes, const int* __restrict__ cls,
        int* __restrict__ tk_idx, float* __restrict__ tk_sc, float* __restrict__ tk_box,
        float* __restrict__ tk_nbox, int* __restrict__ tk_cls,
        float* __restrict__ outz) {
    if (blockIdx.x != 0) {       // zero-fill blocks: slice [kZ0, kZ1)
        v4f z = 0.f;
        size_t stride = (size_t)(gridDim.x - 1) * 1024;
        for (size_t i = kZ0 + (size_t)(blockIdx.x - 1) * 1024 + threadIdx.x;
             i < kZ1; i += stride)
            __builtin_nontemporal_store(z, ((v4f*)outz) + i);
        return;
    }
    __shared__ unsigned long long keys[kTopK];
    __shared__ int wcnt[16];
    __shared__ unsigned sh_cnt;
    int tid = threadIdx.x;
    int lane = tid & 63, wid = tid >> 6;

    unsigned uv[25];
#pragma unroll
    for (int k = 0; k < 25; ++k) {
        int i = tid + k * 1024;
        uv[k] = (i < kNA) ? f2ord(scores[i]) : 0u;  // padding 0: below any real score's ord
    }

    // binary search for uT = exact 1024th-largest ordered-uint; two guided probes
    // (ord(0.25), ord(1.0)+1) shrink the range first — always-correct midpoints.
    unsigned lo = 0u, hi = 0xFFFFFFFFu;
    for (int it = 0; it < 34; ++it) {
        unsigned mid;
        if (it == 0)      mid = 0xBE800000u;      // f2ord(0.25f)
        else if (it == 1) mid = 0xBF800001u;      // f2ord(1.0f)+1
        else {
            mid = (unsigned)(((unsigned long long)lo + (unsigned long long)hi) >> 1);
            if (mid == lo) break;                 // block-uniform
        }
        if (mid <= lo || mid >= hi) continue;     // probe outside range (uniform)
        int c = 0;
#pragma unroll
        for (int k = 0; k < 25; ++k) c += (uv[k] >= mid);   // mid>=1 so padding never counts
#pragma unroll
        for (int off = 32; off >= 1; off >>= 1) c += __shfl_down(c, off);
        __syncthreads();                      // WAR: previous reads of wcnt finished
        if (lane == 0) wcnt[wid] = c;
        __syncthreads();
        int tot = 0;
#pragma unroll
        for (int w = 0; w < 16; ++w) tot += wcnt[w];
        if (tot >= kTopK) lo = mid; else hi = mid;
    }
    unsigned uT = lo;

    // count strictly greater (= count >= uT+1)
    int nGreater;
    {
        int c = 0;
#pragma unroll
        for (int k = 0; k < 25; ++k) c += (uv[k] >= uT + 1u);
#pragma unroll
        for (int off = 32; off >= 1; off >>= 1) c += __shfl_down(c, off);
        __syncthreads();
        if (lane == 0) wcnt[wid] = c;
        __syncthreads();
        int t = 0;
#pragma unroll
        for (int w = 0; w < 16; ++w) t += wcnt[w];
        nGreater = t;
    }
    int krem = kTopK - nGreater;
    if (tid == 0) sh_cnt = 0;
    __syncthreads();

    // compact strictly-greater elements (key embeds ~idx for index tie-break)
#pragma unroll
    for (int k = 0; k < 25; ++k) {
        int i = tid + k * 1024;
        unsigned u = uv[k];
        if (i < kNA && u > uT) {
            unsigned p = atomicAdd(&sh_cnt, 1u);
            keys[p] = ((unsigned long long)u << 32) | (unsigned)(~i);
        }
    }

    // among equals pick the `krem` lowest indices: binary search for index cutoff
    int ilo = 0, ihi = kNA;
    while (ilo < ihi) {
        int mid = (ilo + ihi) >> 1;
        int c = 0;
#pragma unroll
        for (int k = 0; k < 25; ++k) {
            int i = tid + k * 1024;
            c += (i < mid && uv[k] == uT);
        }
#pragma unroll
        for (int off = 32; off >= 1; off >>= 1) c += __shfl_down(c, off);
        __syncthreads();                      // WAR (also covers compaction's keys writes)
        if (lane == 0) wcnt[wid] = c;
        __syncthreads();
        int cc = 0;
#pragma unroll
        for (int w = 0; w < 16; ++w) cc += wcnt[w];
        if (cc >= krem) ihi = mid; else ilo = mid + 1;
    }
#pragma unroll
    for (int k = 0; k < 25; ++k) {
        int i = tid + k * 1024;
        if (i < ilo && uv[k] == uT) {
            unsigned p = atomicAdd(&sh_cnt, 1u);
            keys[p] = ((unsigned long long)uT << 32) | (unsigned)(~i);
        }
    }
    __syncthreads();

    // bitonic sort 1024 keys descending (u desc, then idx asc via ~idx)
    for (int k2 = 2; k2 <= kTopK; k2 <<= 1) {
        for (int j = k2 >> 1; j > 0; j >>= 1) {
            int partner = tid ^ j;
            unsigned long long a = keys[tid], b = keys[partner];
            bool iLower = (tid & j) == 0;
            bool descRegion = (tid & k2) == 0;
            unsigned long long mx = (a > b) ? a : b;
            unsigned long long mn = (a > b) ? b : a;
            unsigned long long res = (iLower == descRegion) ? mx : mn;
            __syncthreads();
            keys[tid] = res;
            __syncthreads();
        }
    }

    unsigned long long key = keys[tid];
    unsigned u = (unsigned)(key >> 32);
    int idx = (int)(~((unsigned)key));
    tk_idx[tid] = idx;
    tk_sc[tid]  = ord2f(u);
    float4 bx = ((const float4*)boxes)[idx];
    ((float4*)tk_box)[tid] = bx;
    int cid = cls[idx];
    float off = (float)cid * kMaxWH;
    float4 nb; nb.x = bx.x + off; nb.y = bx.y + off; nb.z = bx.z + off; nb.w = bx.w + off;
    ((float4*)tk_nbox)[tid] = nb;
    tk_cls[tid] = cid;
}

// ---------------- kernel 3: suppression bitmask (blocks 0..63) + zero share ----
__global__ __launch_bounds__(256) void supmat_k(const float* __restrict__ tk_nbox,
                                                unsigned long long* __restrict__ sup,
                                                float* __restrict__ outz) {
    if (blockIdx.x >= 64) {      // zero-fill blocks: slice [kZ1, kZ2)
        v4f z = 0.f;
        size_t stride = (size_t)(gridDim.x - 64) * 256;
        for (size_t i = kZ1 + (size_t)(blockIdx.x - 64) * 256 + threadIdx.x;
             i < kZ2; i += stride)
            __builtin_nontemporal_store(z, ((v4f*)outz) + i);
        return;
    }
    __shared__ float4 bxs[kTopK];
    int tid = threadIdx.x;
    for (int k = tid; k < kTopK; k += 256) bxs[k] = ((const float4*)tk_nbox)[k];
    __syncthreads();
    int r = tid >> 4, w = tid & 15;
    int i = blockIdx.x * 16 + r;
    float4 a = bxs[i];
    float areaA = (a.z - a.x) * (a.w - a.y);
    unsigned long long bits = 0;
    for (int l = 0; l < 64; ++l) {
        float4 b = bxs[w * 64 + l];
        float xx1 = fmaxf(a.x, b.x), yy1 = fmaxf(a.y, b.y);
        float xx2 = fminf(a.z, b.z), yy2 = fminf(a.w, b.w);
        float iw = fmaxf(xx2 - xx1, 0.f), ih = fmaxf(yy2 - yy1, 0.f);
        float inter = iw * ih;
        float areaB = (b.z - b.x) * (b.w - b.y);
        float iou = inter / (areaA + areaB - inter + 1e-7f);
        if (iou > kIouT) bits |= 1ull << l;
    }
    sup[(size_t)i * 16 + w] = bits;
}

// ---------------- kernel 4: greedy NMS (block 0) + finalize + rowr + zero share -
__global__ __launch_bounds__(256) void nms_k(const float* __restrict__ pred,
        const float* __restrict__ tk_sc, const int* __restrict__ tk_idx,
        const float* __restrict__ tk_box, const int* __restrict__ tk_cls,
        const unsigned long long* __restrict__ sup,
        int* __restrict__ ndet, float* __restrict__ out,
        float* __restrict__ dbox, float* __restrict__ dcoef,
        int4* __restrict__ rowr) {
    if (blockIdx.x != 0) {       // zero-fill blocks: slice [kZ2, kZ3)
        v4f z = 0.f;
        size_t stride = (size_t)(gridDim.x - 1) * 256;
        for (size_t i = kZ2 + (size_t)(blockIdx.x - 1) * 256 + threadIdx.x;
             i < kZ3; i += stride)
            __builtin_nontemporal_store(z, ((v4f*)out) + i);
        return;
    }
    __shared__ unsigned long long buf[2][1024];   // 2 x 8 KB chunks (64 rows x 16 words)
    __shared__ int dslot_lds[kMaxDet];
    __shared__ int sh_nd;
    int tid = threadIdx.x;
    int lane = tid & 63;

    unsigned long long vW = 0;     // lane b of wave0: valid bits of block b
    if (tid < 64) {
        for (int b = 0; b < 16; ++b) {
            unsigned long long bw = __ballot(tk_sc[b * 64 + lane] > kConfT);
            if (lane == b) vW = bw;
        }
    }
    for (int i = tid; i < 1024; i += 256) buf[0][i] = sup[i];   // preload chunk 0

    unsigned long long supW = 0;   // lane w<16: accumulated suppression word w per block
    unsigned long long kws[16];
    for (int b = 0; b < 16; ++b) {
        __syncthreads();           // chunk b ready, buf[(b+1)&1] free
        if (tid >= 64) {           // producers: waves 1-3 stream chunk b+1
            if (b + 1 < 16) {
                for (int i = tid - 64; i < 1024; i += 192)
                    buf[(b + 1) & 1][i] = sup[(size_t)(b + 1) * 1024 + i];
            }
        } else {                   // consumer: wave 0
            const unsigned long long* ch = buf[b & 1];
            unsigned long long s  = __shfl(supW, b);
            unsigned long long vb = __shfl(vW, b);
            unsigned long long kw = 0;
            unsigned long long rbuf[8];
            int w16 = lane & 15;
#pragma unroll
            for (int p = 0; p < 8; ++p) rbuf[p] = ch[p * 16 + w16];
            for (int l = 0; l < 64; ++l) {
                unsigned long long rw = rbuf[l & 7];
                if (l + 8 < 64) rbuf[l & 7] = ch[(l + 8) * 16 + w16];
                unsigned long long rb = __shfl(rw, b);   // intra-block word of row l
                bool kp = ((vb >> l) & 1ull) && !((s >> l) & 1ull);  // wave-uniform
                if (kp) { kw |= 1ull << l; s |= rb; supW |= rw; }
            }
            kws[b] = kw;
        }
    }
    if (tid == 0) {
        int d = 0;
        for (int b = 0; b < 16 && d < kMaxDet; ++b) {
            unsigned long long kw = kws[b];
            for (int l = 0; l < 64 && d < kMaxDet; ++l)
                if ((kw >> l) & 1ull) dslot_lds[d++] = b * 64 + l;
        }
        sh_nd = d;
        *ndet = d;
    }
    __syncthreads();

    // fused finalize: small outputs + mask-kernel inputs + per-det quad ranges
    int n = sh_nd;
    float* fb   = out + 2 * kMaskElems;
    float* fs   = fb + kMaxDet * 4;
    float* fcls = fs + kMaxDet;
    for (int d = tid; d < kMaxDet; d += 256) {
        int4 rr; rr.x = 1; rr.y = 0; rr.z = 1; rr.w = 0;   // empty sentinel
        if (d < n) {
            int t = dslot_lds[d];
            int a = tk_idx[t];
            float4 bx = ((const float4*)tk_box)[t];
            fb[4*d+0] = bx.x; fb[4*d+1] = bx.y; fb[4*d+2] = bx.z; fb[4*d+3] = bx.w;
            fs[d] = tk_sc[t];
            fcls[d] = (float)tk_cls[t];
            ((float4*)dbox)[d] = bx;
            const float* cp = pred + (size_t)a * kStride + 5 + kNC;
            for (int c = 0; c < kNM; ++c) dcoef[d * kNM + c] = cp[c];
            // exact integer pixel ranges of the crop predicate
            int i_lo = max(0, (int)ceilf(bx.y));
            int i_hi = min(kImg - 1, (int)ceilf(bx.w) - 1);
            int j_lo = max(0, (int)ceilf(bx.x));
            int j_hi = min(kImg - 1, (int)ceilf(bx.z) - 1);
            if (i_lo <= i_hi && j_lo <= j_hi) {
                rr.x = i_lo; rr.y = i_hi; rr.z = j_lo >> 2; rr.w = j_hi >> 2;
            }
        } else {
            fb[4*d+0] = 0.f; fb[4*d+1] = 0.f; fb[4*d+2] = 0.f; fb[4*d+3] = 0.f;
            fs[d] = 0.f; fcls[d] = -1.0f;
            float4 z; z.x = z.y = z.z = z.w = 0.f;
            ((float4*)dbox)[d] = z;
            for (int c = 0; c < kNM; ++c) dcoef[d * kNM + c] = 0.f;
        }
        rowr[d] = rr;
    }
}

// ---------------- kernel 5: finalize = box-quad patches + skip-zero of the rest -
// Patch block d writes exactly the quads {i in [rr.x,rr.y]} x {jq in [rr.z,rr.w]}
// (per-lane in-box test inside boundary quads; out-of-box lanes get exact 0).
// Zero blocks cover quads [kZ3, kN4) EXCEPT that owned set — disjoint addresses,
// so both run concurrently in one kernel, overlapping the zero tail with patch
// compute. Quads < kZ3 inside rects were pre-zeroed and are overwritten here.
constexpr int kPatch = 34;    // proto-patch span for a <=122 px box: <=33 (+1 slack)

__global__ __launch_bounds__(256) void finalize_k(const float* __restrict__ protos,
        const float* __restrict__ dbox, const float* __restrict__ dcoef,
        const int4* __restrict__ rowr, float* __restrict__ out) {
    int tid = threadIdx.x;
    if (blockIdx.x >= kMaxDet) {              // ---- zero blocks with quad skip ----
        __shared__ int4 rr_lds[kMaxDet];
        for (int t = tid; t < kMaxDet; t += 256) rr_lds[t] = rowr[t];
        __syncthreads();
        v4f z = 0.f;
        size_t stride = (size_t)(gridDim.x - kMaxDet) * 256;
        for (size_t q = kZ3 + (size_t)(blockIdx.x - kMaxDet) * 256 + tid;
             q < kN4; q += stride) {
            unsigned qr = (unsigned)((q >= kQSlices) ? (q - kQSlices) : q);  // fold b onto f
            unsigned d    = qr / kQPerSlice;            // const-div -> mulhi+shift
            unsigned rowq = qr - d * kQPerSlice;
            unsigned i    = rowq / kQPerRow;
            unsigned jq   = rowq - i * kQPerRow;
            int4 rr = rr_lds[d];                        // lanes share d -> LDS broadcast
            bool own = ((int)i >= rr.x) & ((int)i <= rr.y) &
                       ((int)jq >= rr.z) & ((int)jq <= rr.w);
            if (!own)
                __builtin_nontemporal_store(z, ((v4f*)out) + q);
        }
        return;
    }
    // ---- patch block for detection d ----
    int d = blockIdx.x;
    int4 rr = rowr[d];
    if (rr.x > rr.y) return;                  // block-uniform (covers d >= ndet / empty)
    float4 bx = ((const float4*)dbox)[d];
    int i_lo = rr.x, i_hi = rr.y;
    int j_lo = max(0, (int)ceilf(bx.x));
    int j_hi = min(kImg - 1, (int)ceilf(bx.z) - 1);

    int py_lo = min(159, max(0, (int)floorf(((float)i_lo + 0.5f) * 0.25f - 0.5f)));
    int py_hi = min(159, max(0, (int)floorf(((float)i_hi + 0.5f) * 0.25f - 0.5f) + 1));
    int px_lo = min(159, max(0, (int)floorf(((float)j_lo + 0.5f) * 0.25f - 0.5f)));
    int px_hi = min(159, max(0, (int)floorf(((float)j_hi + 0.5f) * 0.25f - 0.5f) + 1));
    int ph = py_hi - py_lo + 1, pw = px_hi - px_lo + 1;
    if (ph > kPatch) ph = kPatch;
    if (pw > kPatch) pw = kPatch;

    __shared__ float coef[kNM];
    __shared__ float patch[kPatch * kPatch];
    if (tid < kNM) coef[tid] = dcoef[d * kNM + tid];
    __syncthreads();
    int cells = ph * pw;
    for (int c = tid; c < cells; c += 256) {
        int py = py_lo + c / pw, px = px_lo + c % pw;
        const float* pp = protos + (size_t)py * kPHW + px;
        float z = 0.f;
#pragma unroll
        for (int m = 0; m < kNM; ++m) z = fmaf(coef[m], pp[(size_t)m * kPHW * kPHW], z);
        patch[c] = 1.0f / (1.0f + expf(-z));
    }
    __syncthreads();

    float* mf = out + (size_t)d * (kImg * kImg);
    float* mb = out + kMaskElems + (size_t)d * (kImg * kImg);
    int H  = i_hi - i_lo + 1;
    int nq = rr.w - rr.z + 1;                 // <= 32 quads across the box
    int work = H * nq;
    for (int w = tid; w < work; w += 256) {
        int rrow = w / nq;
        int jqo  = w - rrow * nq;
        int i  = i_lo + rrow;
        int j0 = (rr.z + jqo) * 4;
        float sy = fminf(fmaxf(((float)i + 0.5f) * 0.25f - 0.5f, 0.f), 159.f);
        int yy0 = (int)sy; float fy = sy - (float)yy0;
        int yy1i = min(yy0 + 1, 159);
        const float* prow0 = &patch[(yy0 - py_lo) * pw - px_lo];
        const float* prow1 = &patch[(yy1i - py_lo) * pw - px_lo];
        v4f vf = 0.f;
        v4f vb = 0.f;
#pragma unroll
        for (int t = 0; t < 4; ++t) {
            int j = j0 + t;
            if (j >= j_lo && j <= j_hi) {
                float sx = fminf(fmaxf(((float)j + 0.5f) * 0.25f - 0.5f, 0.f), 159.f);
                int xx0 = (int)sx; float fx = sx - (float)xx0;
                int xx1i = min(xx0 + 1, 159);
                float v00 = prow0[xx0], v01 = prow0[xx1i];
                float v10 = prow1[xx0], v11 = prow1[xx1i];
                float top = (1.f - fx) * v00 + fx * v01;
                float bot = (1.f - fx) * v10 + fx * v11;
                float m = (1.f - fy) * top + fy * bot;
                vf[t] = m;
                vb[t] = (m > 0.5f) ? 1.f : 0.f;
            }
        }
        __builtin_nontemporal_store(vf, (v4f*)(mf + (size_t)i * kImg + j0));
        __builtin_nontemporal_store(vb, (v4f*)(mb + (size_t)i * kImg + j0));
    }
}

// ---------------- launcher ----------------
extern "C" void kernel_launch(void* const* d_in, const int* in_sizes, int n_in,
                              void* d_out, int out_size, void* d_ws, size_t ws_size,
                              hipStream_t stream) {
    const float* pred   = (const float*)d_in[0];
    const float* protos = (const float*)d_in[1];
    float* out = (float*)d_out;
    char* ws = (char*)d_ws;

    float* s_scores = (float*)(ws + O_SCORES);
    float* s_boxes  = (float*)(ws + O_BOXES);
    int*   s_cls    = (int*)  (ws + O_CLS);
    int*   tk_idx   = (int*)  (ws + O_TKIDX);
    float* tk_sc    = (float*)(ws + O_TKSC);
    float* tk_box   = (float*)(ws + O_TKBOX);
    float* tk_nbox  = (float*)(ws + O_TKNBOX);
    int*   tk_cls   = (int*)  (ws + O_TKCLS);
    unsigned long long* sup = (unsigned long long*)(ws + O_SUP);
    int*   ndet     = (int*)  (ws + O_NDET);
    float* dbox     = (float*)(ws + O_DBOX);
    float* dcoef    = (float*)(ws + O_DCOEF);
    int4*  rowr     = (int4*) (ws + O_ROWR);

    decode_k<<<dim3(kDecBlocks + kZDecB), dim3(kDecThr), 0, stream>>>(pred, s_scores, s_boxes, s_cls, out);
    topk_k<<<dim3(1 + kZTopkB), dim3(1024), 0, stream>>>(s_scores, s_boxes, s_cls,
                                               tk_idx, tk_sc, tk_box, tk_nbox, tk_cls, out);
    supmat_k<<<dim3(64 + kZSupB), dim3(256), 0, stream>>>(tk_nbox, sup, out);
    nms_k<<<dim3(1 + kZNmsB), dim3(256), 0, stream>>>(pred, tk_sc, tk_idx, tk_box, tk_cls, sup,
                                             ndet, out, dbox, dcoef, rowr);
    finalize_k<<<dim3(kMaxDet + kZFinB), dim3(256), 0, stream>>>(protos, dbox, dcoef, rowr, out);
}

// Round 5
// 1080.469 us; speedup vs baseline: 1.0831x; 1.0831x over previous
//
#include <hip/hip_runtime.h>

// ---------------- constants ----------------
constexpr int   kNA     = 25200;
constexpr int   kStride = 117;      // 4 box + 1 obj + 80 cls + 32 coef
constexpr int   kNC     = 80;
constexpr int   kNM     = 32;
constexpr int   kTopK   = 1024;
constexpr int   kMaxDet = 300;
constexpr int   kImg    = 640;
constexpr int   kPHW    = 160;
constexpr float kConfT  = 0.25f;
constexpr float kIouT   = 0.45f;
constexpr float kMaxWH  = 7680.0f;

constexpr unsigned long long kMaskElems = 300ull * 640ull * 640ull; // 122,880,000

typedef float v4f __attribute__((ext_vector_type(4)));

// mask region: 61,440,000 float4 quads (983 MB), zeroed entirely BEFORE patch_k.
// Partition packs ALL zeroing under the serial stages (r2 structure — champion);
// r3/r4 proved trailing zero in the patch kernel is a net loss.
constexpr size_t kN4 = 61440000;
constexpr size_t kZ0 = 4000000;      // decode share  (64 MB ~ 10 us)
constexpr size_t kZ1 = 29600000;     // topk share    (410 MB ~ 66 us)
constexpr size_t kZ2 = 35744000;     // supmat share  (98 MB ~ 16 us)
// nms zeroes [kZ2, kN4)              (411 MB ~ 66 us)

constexpr int kZDecB  = 512;   // extra 128-thr zero blocks in decode_k
constexpr int kZTopkB = 512;   // extra 1024-thr zero blocks in topk_k
constexpr int kZSupB  = 320;   // extra 256-thr zero blocks in supmat_k
constexpr int kZNmsB  = 1024;  // extra 256-thr zero blocks in nms_k

// ---------------- ws layout (bytes) ----------------
constexpr size_t O_SCORES = 0;        // 25200 f32
constexpr size_t O_BOXES  = 100864;   // 25200*4 f32 (16B aligned)
constexpr size_t O_CLS    = 504064;   // 25200 i32
constexpr size_t O_TKIDX  = 604864;   // 1024 i32
constexpr size_t O_TKSC   = 608960;   // 1024 f32
constexpr size_t O_TKBOX  = 613056;   // 1024*4 f32
constexpr size_t O_TKNBOX = 629440;   // 1024*4 f32 (class-offset boxes)
constexpr size_t O_TKCLS  = 645824;   // 1024 i32
constexpr size_t O_SUP    = 649984;   // 1024*16 u64 = 131072
constexpr size_t O_NDET   = 782336;   // 1 i32
constexpr size_t O_DBOX   = 782400;   // 300*4 f32
constexpr size_t O_DCOEF  = 787264;   // 300*32 f32
// total < 1 MB

// ---------------- kernel 1: decode (LDS-staged) + zero share [0, kZ0) ---------
constexpr int kDecRows = 64;
constexpr int kDecThr  = 128;
constexpr int kDecBlocks = (kNA + kDecRows - 1) / kDecRows;   // 394
__global__ __launch_bounds__(kDecThr) void decode_k(const float* __restrict__ pred,
        float* __restrict__ scores, float* __restrict__ boxes, int* __restrict__ cls,
        float* __restrict__ outz) {
    if (blockIdx.x >= kDecBlocks) {      // zero-fill blocks
        v4f z = 0.f;
        size_t stride = (size_t)(gridDim.x - kDecBlocks) * kDecThr;
        for (size_t i = (size_t)(blockIdx.x - kDecBlocks) * kDecThr + threadIdx.x;
             i < kZ0; i += stride)
            __builtin_nontemporal_store(z, ((v4f*)outz) + i);
        return;
    }
    __shared__ float rows[kDecRows * kStride];   // 29,952 B -> 5 blocks/CU
    int base = blockIdx.x * kDecRows;
    int nrows = min(kDecRows, kNA - base);
    int total = nrows * kStride;
    const float* src = pred + (size_t)base * kStride;
    for (int i = threadIdx.x; i < total; i += kDecThr) rows[i] = src[i];
    __syncthreads();
    int r = threadIdx.x;
    if (r >= nrows) return;
    int a = base + r;
    const float* p = rows + r * kStride;
    float obj = p[4];
    float best = -1.0f; int bj = 0;
    for (int c = 0; c < kNC; ++c) {
        float v = p[5 + c] * obj;           // same single-rounding product as reference
        if (v > best) { best = v; bj = c; } // strict > keeps first max (argmax semantics)
    }
    bool valid = (obj > kConfT) && (best > kConfT);
    scores[a] = valid ? best : -1.0f;
    float cx = p[0], cy = p[1], w = p[2], h = p[3];
    float hw = w * 0.5f, hh = h * 0.5f;
    boxes[4*a+0] = cx - hw; boxes[4*a+1] = cy - hh;
    boxes[4*a+2] = cx + hw; boxes[4*a+3] = cy + hh;
    cls[a] = bj;
}

// ---------------- kernel 2: exact top-1024 (block 0) + zero share --------------
__device__ __forceinline__ unsigned f2ord(float f) {
    unsigned b = __float_as_uint(f);
    return (b & 0x80000000u) ? ~b : (b | 0x80000000u);
}
__device__ __forceinline__ float ord2f(unsigned u) {
    unsigned b = (u & 0x80000000u) ? (u ^ 0x80000000u) : ~u;
    return __uint_as_float(b);
}

__global__ __launch_bounds__(1024) void topk_k(const float* __restrict__ scores,
        const float* __restrict__ boxes, const int* __restrict__ cls,
        int* __restrict__ tk_idx, float* __restrict__ tk_sc, float* __restrict__ tk_box,
        float* __restrict__ tk_nbox, int* __restrict__ tk_cls,
        float* __restrict__ outz) {
    if (blockIdx.x != 0) {       // zero-fill blocks: slice [kZ0, kZ1)
        v4f z = 0.f;
        size_t stride = (size_t)(gridDim.x - 1) * 1024;
        for (size_t i = kZ0 + (size_t)(blockIdx.x - 1) * 1024 + threadIdx.x;
             i < kZ1; i += stride)
            __builtin_nontemporal_store(z, ((v4f*)outz) + i);
        return;
    }
    __shared__ unsigned long long keys[kTopK];
    __shared__ int wcnt[16];
    __shared__ unsigned sh_cnt;
    int tid = threadIdx.x;
    int lane = tid & 63, wid = tid >> 6;

    unsigned uv[25];
#pragma unroll
    for (int k = 0; k < 25; ++k) {
        int i = tid + k * 1024;
        uv[k] = (i < kNA) ? f2ord(scores[i]) : 0u;  // padding 0: below any real score's ord
    }

    // binary search for uT = exact 1024th-largest ordered-uint; two guided probes
    // (ord(0.25), ord(1.0)+1) shrink the range first — always-correct midpoints.
    unsigned lo = 0u, hi = 0xFFFFFFFFu;
    for (int it = 0; it < 34; ++it) {
        unsigned mid;
        if (it == 0)      mid = 0xBE800000u;      // f2ord(0.25f)
        else if (it == 1) mid = 0xBF800001u;      // f2ord(1.0f)+1
        else {
            mid = (unsigned)(((unsigned long long)lo + (unsigned long long)hi) >> 1);
            if (mid == lo) break;                 // block-uniform
        }
        if (mid <= lo || mid >= hi) continue;     // probe outside range (uniform)
        int c = 0;
#pragma unroll
        for (int k = 0; k < 25; ++k) c += (uv[k] >= mid);   // mid>=1 so padding never counts
#pragma unroll
        for (int off = 32; off >= 1; off >>= 1) c += __shfl_down(c, off);
        __syncthreads();                      // WAR: previous reads of wcnt finished
        if (lane == 0) wcnt[wid] = c;
        __syncthreads();
        int tot = 0;
#pragma unroll
        for (int w = 0; w < 16; ++w) tot += wcnt[w];
        if (tot >= kTopK) lo = mid; else hi = mid;
    }
    unsigned uT = lo;

    // count strictly greater (= count >= uT+1)
    int nGreater;
    {
        int c = 0;
#pragma unroll
        for (int k = 0; k < 25; ++k) c += (uv[k] >= uT + 1u);
#pragma unroll
        for (int off = 32; off >= 1; off >>= 1) c += __shfl_down(c, off);
        __syncthreads();
        if (lane == 0) wcnt[wid] = c;
        __syncthreads();
        int t = 0;
#pragma unroll
        for (int w = 0; w < 16; ++w) t += wcnt[w];
        nGreater = t;
    }
    int krem = kTopK - nGreater;
    if (tid == 0) sh_cnt = 0;
    __syncthreads();

    // compact strictly-greater elements (key embeds ~idx for index tie-break)
#pragma unroll
    for (int k = 0; k < 25; ++k) {
        int i = tid + k * 1024;
        unsigned u = uv[k];
        if (i < kNA && u > uT) {
            unsigned p = atomicAdd(&sh_cnt, 1u);
            keys[p] = ((unsigned long long)u << 32) | (unsigned)(~i);
        }
    }

    // among equals pick the `krem` lowest indices: binary search for index cutoff
    int ilo = 0, ihi = kNA;
    while (ilo < ihi) {
        int mid = (ilo + ihi) >> 1;
        int c = 0;
#pragma unroll
        for (int k = 0; k < 25; ++k) {
            int i = tid + k * 1024;
            c += (i < mid && uv[k] == uT);
        }
#pragma unroll
        for (int off = 32; off >= 1; off >>= 1) c += __shfl_down(c, off);
        __syncthreads();                      // WAR (also covers compaction's keys writes)
        if (lane == 0) wcnt[wid] = c;
        __syncthreads();
        int cc = 0;
#pragma unroll
        for (int w = 0; w < 16; ++w) cc += wcnt[w];
        if (cc >= krem) ihi = mid; else ilo = mid + 1;
    }
#pragma unroll
    for (int k = 0; k < 25; ++k) {
        int i = tid + k * 1024;
        if (i < ilo && uv[k] == uT) {
            unsigned p = atomicAdd(&sh_cnt, 1u);
            keys[p] = ((unsigned long long)uT << 32) | (unsigned)(~i);
        }
    }
    __syncthreads();

    // bitonic sort 1024 keys descending (u desc, then idx asc via ~idx)
    for (int k2 = 2; k2 <= kTopK; k2 <<= 1) {
        for (int j = k2 >> 1; j > 0; j >>= 1) {
            int partner = tid ^ j;
            unsigned long long a = keys[tid], b = keys[partner];
            bool iLower = (tid & j) == 0;
            bool descRegion = (tid & k2) == 0;
            unsigned long long mx = (a > b) ? a : b;
            unsigned long long mn = (a > b) ? b : a;
            unsigned long long res = (iLower == descRegion) ? mx : mn;
            __syncthreads();
            keys[tid] = res;
            __syncthreads();
        }
    }

    unsigned long long key = keys[tid];
    unsigned u = (unsigned)(key >> 32);
    int idx = (int)(~((unsigned)key));
    tk_idx[tid] = idx;
    tk_sc[tid]  = ord2f(u);
    float4 bx = ((const float4*)boxes)[idx];
    ((float4*)tk_box)[tid] = bx;
    int cid = cls[idx];
    float off = (float)cid * kMaxWH;
    float4 nb; nb.x = bx.x + off; nb.y = bx.y + off; nb.z = bx.z + off; nb.w = bx.w + off;
    ((float4*)tk_nbox)[tid] = nb;
    tk_cls[tid] = cid;
}

// ---------------- kernel 3: suppression bitmask (blocks 0..63) + zero share ----
__global__ __launch_bounds__(256) void supmat_k(const float* __restrict__ tk_nbox,
                                                unsigned long long* __restrict__ sup,
                                                float* __restrict__ outz) {
    if (blockIdx.x >= 64) {      // zero-fill blocks: slice [kZ1, kZ2)
        v4f z = 0.f;
        size_t stride = (size_t)(gridDim.x - 64) * 256;
        for (size_t i = kZ1 + (size_t)(blockIdx.x - 64) * 256 + threadIdx.x;
             i < kZ2; i += stride)
            __builtin_nontemporal_store(z, ((v4f*)outz) + i);
        return;
    }
    __shared__ float4 bxs[kTopK];
    int tid = threadIdx.x;
    for (int k = tid; k < kTopK; k += 256) bxs[k] = ((const float4*)tk_nbox)[k];
    __syncthreads();
    int r = tid >> 4, w = tid & 15;
    int i = blockIdx.x * 16 + r;
    float4 a = bxs[i];
    float areaA = (a.z - a.x) * (a.w - a.y);
    unsigned long long bits = 0;
    for (int l = 0; l < 64; ++l) {
        float4 b = bxs[w * 64 + l];
        float xx1 = fmaxf(a.x, b.x), yy1 = fmaxf(a.y, b.y);
        float xx2 = fminf(a.z, b.z), yy2 = fminf(a.w, b.w);
        float iw = fmaxf(xx2 - xx1, 0.f), ih = fmaxf(yy2 - yy1, 0.f);
        float inter = iw * ih;
        float areaB = (b.z - b.x) * (b.w - b.y);
        float iou = inter / (areaA + areaB - inter + 1e-7f);
        if (iou > kIouT) bits |= 1ull << l;
    }
    sup[(size_t)i * 16 + w] = bits;
}

// ---------------- kernel 4: greedy NMS (block 0) + finalize + zero share -------
__global__ __launch_bounds__(256) void nms_k(const float* __restrict__ pred,
        const float* __restrict__ tk_sc, const int* __restrict__ tk_idx,
        const float* __restrict__ tk_box, const int* __restrict__ tk_cls,
        const unsigned long long* __restrict__ sup,
        int* __restrict__ ndet, float* __restrict__ out,
        float* __restrict__ dbox, float* __restrict__ dcoef) {
    if (blockIdx.x != 0) {       // zero-fill blocks: slice [kZ2, kN4)
        v4f z = 0.f;
        size_t stride = (size_t)(gridDim.x - 1) * 256;
        for (size_t i = kZ2 + (size_t)(blockIdx.x - 1) * 256 + threadIdx.x;
             i < kN4; i += stride)
            __builtin_nontemporal_store(z, ((v4f*)out) + i);
        return;
    }
    __shared__ unsigned long long buf[2][1024];   // 2 x 8 KB chunks (64 rows x 16 words)
    __shared__ int dslot_lds[kMaxDet];
    __shared__ int sh_nd;
    int tid = threadIdx.x;
    int lane = tid & 63;

    unsigned long long vW = 0;     // lane b of wave0: valid bits of block b
    if (tid < 64) {
        for (int b = 0; b < 16; ++b) {
            unsigned long long bw = __ballot(tk_sc[b * 64 + lane] > kConfT);
            if (lane == b) vW = bw;
        }
    }
    for (int i = tid; i < 1024; i += 256) buf[0][i] = sup[i];   // preload chunk 0

    unsigned long long supW = 0;   // lane w<16: accumulated suppression word w per block
    unsigned long long kws[16];
    for (int b = 0; b < 16; ++b) {
        __syncthreads();           // chunk b ready, buf[(b+1)&1] free
        if (tid >= 64) {           // producers: waves 1-3 stream chunk b+1
            if (b + 1 < 16) {
                for (int i = tid - 64; i < 1024; i += 192)
                    buf[(b + 1) & 1][i] = sup[(size_t)(b + 1) * 1024 + i];
            }
        } else {                   // consumer: wave 0
            const unsigned long long* ch = buf[b & 1];
            unsigned long long s  = __shfl(supW, b);
            unsigned long long vb = __shfl(vW, b);
            unsigned long long kw = 0;
            unsigned long long rbuf[8];
            int w16 = lane & 15;
#pragma unroll
            for (int p = 0; p < 8; ++p) rbuf[p] = ch[p * 16 + w16];
            for (int l = 0; l < 64; ++l) {
                unsigned long long rw = rbuf[l & 7];
                if (l + 8 < 64) rbuf[l & 7] = ch[(l + 8) * 16 + w16];
                unsigned long long rb = __shfl(rw, b);   // intra-block word of row l
                bool kp = ((vb >> l) & 1ull) && !((s >> l) & 1ull);  // wave-uniform
                if (kp) { kw |= 1ull << l; s |= rb; supW |= rw; }
            }
            kws[b] = kw;
        }
    }
    if (tid == 0) {
        int d = 0;
        for (int b = 0; b < 16 && d < kMaxDet; ++b) {
            unsigned long long kw = kws[b];
            for (int l = 0; l < 64 && d < kMaxDet; ++l)
                if ((kw >> l) & 1ull) dslot_lds[d++] = b * 64 + l;
        }
        sh_nd = d;
        *ndet = d;
    }
    __syncthreads();

    // fused finalize: small outputs + mask-kernel inputs
    int n = sh_nd;
    float* fb   = out + 2 * kMaskElems;
    float* fs   = fb + kMaxDet * 4;
    float* fcls = fs + kMaxDet;
    for (int d = tid; d < kMaxDet; d += 256) {
        if (d < n) {
            int t = dslot_lds[d];
            int a = tk_idx[t];
            float4 bx = ((const float4*)tk_box)[t];
            fb[4*d+0] = bx.x; fb[4*d+1] = bx.y; fb[4*d+2] = bx.z; fb[4*d+3] = bx.w;
            fs[d] = tk_sc[t];
            fcls[d] = (float)tk_cls[t];
            ((float4*)dbox)[d] = bx;
            const float* cp = pred + (size_t)a * kStride + 5 + kNC;
            for (int c = 0; c < kNM; ++c) dcoef[d * kNM + c] = cp[c];
        } else {
            fb[4*d+0] = 0.f; fb[4*d+1] = 0.f; fb[4*d+2] = 0.f; fb[4*d+3] = 0.f;
            fs[d] = 0.f; fcls[d] = -1.0f;
            float4 z; z.x = z.y = z.z = z.w = 0.f;
            ((float4*)dbox)[d] = z;
            for (int c = 0; c < kNM; ++c) dcoef[d * kNM + c] = 0.f;
        }
    }
}

// ---------------- kernel 5: box-rect mask writes, 4 row-quarters per detection --
// Background is exactly 0 (zeroed by the shares above); blocks write only pixels
// with (j>=x1 && j<x2 && i>=y1 && i<y2). 4 blocks per detection (row-quarters)
// -> 1200 blocks ~ 4.7/CU: hides the strided proto-load latency that made the
// 300-block version latency-bound (~35 us -> ~12 us predicted).
constexpr int kSplit   = 4;
constexpr int kPatchH  = 12;  // proto rows for <=31 pixel rows: ceil(31/4)+3 slack
constexpr int kPatchW  = 34;  // proto cols for <=122 px box width

__global__ __launch_bounds__(256) void patch_k(const float* __restrict__ protos,
        const float* __restrict__ dbox, const float* __restrict__ dcoef,
        const int* __restrict__ ndet, float* __restrict__ out) {
    int d    = blockIdx.x >> 2;
    int part = blockIdx.x & 3;
    if (d >= *ndet) return;                       // block-uniform
    float4 bx = ((const float4*)dbox)[d];
    float x1 = bx.x, y1 = bx.y, x2 = bx.z, y2 = bx.w;

    // exact integer pixel range satisfying the reference crop predicate
    int i_lo = max(0, (int)ceilf(y1));
    int i_hi = min(kImg - 1, (int)ceilf(y2) - 1);
    int j_lo = max(0, (int)ceilf(x1));
    int j_hi = min(kImg - 1, (int)ceilf(x2) - 1);
    if (i_lo > i_hi || j_lo > j_hi) return;       // block-uniform

    // this block's row quarter
    int H  = i_hi - i_lo + 1;
    int r0 = i_lo + (H * part) / kSplit;
    int r1 = i_lo + (H * (part + 1)) / kSplit - 1;
    if (r0 > r1) return;                          // block-uniform

    int py_lo = min(159, max(0, (int)floorf(((float)r0 + 0.5f) * 0.25f - 0.5f)));
    int py_hi = min(159, max(0, (int)floorf(((float)r1 + 0.5f) * 0.25f - 0.5f) + 1));
    int px_lo = min(159, max(0, (int)floorf(((float)j_lo + 0.5f) * 0.25f - 0.5f)));
    int px_hi = min(159, max(0, (int)floorf(((float)j_hi + 0.5f) * 0.25f - 0.5f) + 1));
    int ph = py_hi - py_lo + 1, pw = px_hi - px_lo + 1;
    if (ph > kPatchH) ph = kPatchH;
    if (pw > kPatchW) pw = kPatchW;

    int tid = threadIdx.x;
    __shared__ float coef[kNM];
    __shared__ float patch[kPatchH * kPatchW];
    if (tid < kNM) coef[tid] = dcoef[d * kNM + tid];
    __syncthreads();
    int cells = ph * pw;
    for (int c = tid; c < cells; c += 256) {
        int py = py_lo + c / pw, px = px_lo + c % pw;
        const float* pp = protos + (size_t)py * kPHW + px;
        float z = 0.f;
#pragma unroll
        for (int m = 0; m < kNM; ++m) z = fmaf(coef[m], pp[(size_t)m * kPHW * kPHW], z);
        patch[c] = 1.0f / (1.0f + expf(-z));
    }
    __syncthreads();

    float* mf = out + (size_t)d * (kImg * kImg);
    float* mb = out + kMaskElems + (size_t)d * (kImg * kImg);
    int jq_lo = j_lo >> 2, jq_hi = j_hi >> 2;
    int nq = jq_hi - jq_lo + 1;                   // <= 32 quads across the box
    int Hq = r1 - r0 + 1;
    int work = Hq * nq;
    for (int w = tid; w < work; w += 256) {
        int rrow = w / nq;
        int jqo  = w - rrow * nq;
        int i  = r0 + rrow;
        int j0 = (jq_lo + jqo) * 4;
        float sy = fminf(fmaxf(((float)i + 0.5f) * 0.25f - 0.5f, 0.f), 159.f);
        int yy0 = (int)sy; float fy = sy - (float)yy0;
        int yy1i = min(yy0 + 1, 159);
        const float* prow0 = &patch[(yy0 - py_lo) * pw - px_lo];
        const float* prow1 = &patch[(yy1i - py_lo) * pw - px_lo];
        v4f vf = 0.f;
        v4f vb = 0.f;
#pragma unroll
        for (int t = 0; t < 4; ++t) {
            int j = j0 + t;
            if (j >= j_lo && j <= j_hi) {
                float sx = fminf(fmaxf(((float)j + 0.5f) * 0.25f - 0.5f, 0.f), 159.f);
                int xx0 = (int)sx; float fx = sx - (float)xx0;
                int xx1i = min(xx0 + 1, 159);
                float v00 = prow0[xx0], v01 = prow0[xx1i];
                float v10 = prow1[xx0], v11 = prow1[xx1i];
                float top = (1.f - fx) * v00 + fx * v01;
                float bot = (1.f - fx) * v10 + fx * v11;
                float m = (1.f - fy) * top + fy * bot;
                vf[t] = m;
                vb[t] = (m > 0.5f) ? 1.f : 0.f;
            }
        }
        __builtin_nontemporal_store(vf, (v4f*)(mf + (size_t)i * kImg + j0));
        __builtin_nontemporal_store(vb, (v4f*)(mb + (size_t)i * kImg + j0));
    }
}

// ---------------- launcher ----------------
extern "C" void kernel_launch(void* const* d_in, const int* in_sizes, int n_in,
                              void* d_out, int out_size, void* d_ws, size_t ws_size,
                              hipStream_t stream) {
    const float* pred   = (const float*)d_in[0];
    const float* protos = (const float*)d_in[1];
    float* out = (float*)d_out;
    char* ws = (char*)d_ws;

    float* s_scores = (float*)(ws + O_SCORES);
    float* s_boxes  = (float*)(ws + O_BOXES);
    int*   s_cls    = (int*)  (ws + O_CLS);
    int*   tk_idx   = (int*)  (ws + O_TKIDX);
    float* tk_sc    = (float*)(ws + O_TKSC);
    float* tk_box   = (float*)(ws + O_TKBOX);
    float* tk_nbox  = (float*)(ws + O_TKNBOX);
    int*   tk_cls   = (int*)  (ws + O_TKCLS);
    unsigned long long* sup = (unsigned long long*)(ws + O_SUP);
    int*   ndet     = (int*)  (ws + O_NDET);
    float* dbox     = (float*)(ws + O_DBOX);
    float* dcoef    = (float*)(ws + O_DCOEF);

    decode_k<<<dim3(kDecBlocks + kZDecB), dim3(kDecThr), 0, stream>>>(pred, s_scores, s_boxes, s_cls, out);
    topk_k<<<dim3(1 + kZTopkB), dim3(1024), 0, stream>>>(s_scores, s_boxes, s_cls,
                                               tk_idx, tk_sc, tk_box, tk_nbox, tk_cls, out);
    supmat_k<<<dim3(64 + kZSupB), dim3(256), 0, stream>>>(tk_nbox, sup, out);
    nms_k<<<dim3(1 + kZNmsB), dim3(256), 0, stream>>>(pred, tk_sc, tk_idx, tk_box, tk_cls, sup,
                                             ndet, out, dbox, dcoef);
    patch_k<<<dim3(kMaxDet * kSplit), dim3(256), 0, stream>>>(protos, dbox, dcoef, ndet, out);
}